// Round 2
// baseline (232.473 us; speedup 1.0000x reference)
//
#include <hip/hip_runtime.h>
#include <math.h>

#define NQ 12
#define NS 4096
#define TT 32
#define BB 256
#define HH 128

// ---------- compile-time CNOT-layer permutations (exactly per reference _cnot) ----------
constexpr unsigned cnot_g(unsigned x, int w, int r){
    int pc = 11 - w;                    // control wire w -> bit 11-w
    int pt = 11 - ((w + r) % 12);       // target wire (w+r)%12
    return x ^ (((x >> pc) & 1u) << pt);
}
// state_new[i] = state_old[Fperm(i,r)] after the 12 sequential CNOTs of a layer
constexpr unsigned Fperm(unsigned i, int r){
    unsigned x = i;
    for (int w = 11; w >= 0; --w) x = cnot_g(x, w, r);
    return x;
}
constexpr unsigned Finv(unsigned i, int r){   // inverse permutation
    unsigned x = i;
    for (int w = 0; w < 12; ++w) x = cnot_g(x, w, r);
    return x;
}
// closed form of Fperm(.,1) (layer 0, r=1)
constexpr unsigned F0closed(unsigned i){
    return i ^ ((i >> 1) & 0x7FFu) ^ ((i & 1u) << 10) ^ ((i & 1u) << 11);
}
// All maps are GF(2)-linear (XOR of bit-selects), so basis-vector equality
// implies equality everywhere. Keep constexpr cost ~500 calls (step limit!).
constexpr bool check_all(){
    for (int b = 0; b < NQ; ++b){
        const unsigned e = 1u << b;
        if (F0closed(e) != Fperm(e,1)) return false;
        if (Fperm(Finv(e,1),1) != e) return false;
        if (Fperm(Finv(e,2),2) != e) return false;
    }
    if (F0closed(0u) != 0u || Fperm(0u,1) != 0u || Finv(0u,2) != 0u) return false;
    if (F0closed(0x5A3u) != Fperm(0x5A3u,1)) return false;        // linearity spot-checks
    if (Fperm(Finv(0xABCu,2),2) != 0xABCu) return false;
    return true;
}
static_assert(check_all(), "CNOT permutation closed forms wrong");
// sign-parity masks: bit_{11-k}(Finv(j,2)) == parity(j & maskM(k))
constexpr unsigned maskM(int k){
    unsigned m = 0;
    for (int b = 0; b < NQ; ++b) m |= ((Finv(1u<<b, 2) >> (11 - k)) & 1u) << b;
    return m;
}

__device__ __forceinline__ float2 cmul(float2 a, float2 b){
    return make_float2(fmaf(a.x, b.x, -a.y * b.y), fmaf(a.x, b.y, a.y * b.x));
}
// LDS bank swizzle (involution, XOR-linear)
__device__ __forceinline__ int swz(int u){ return u ^ ((u >> 4) & 0xF); }

// apply 4 layer-1 Rot gates on the 4 thread-local qubit bits; wire = wbase - lb
__device__ __forceinline__ void rot4(float2* s, const float (*m1)[8], int wbase){
    #pragma unroll
    for (int lb = 0; lb < 4; ++lb){
        const float* m = m1[wbase - lb];
        const float m00r=m[0], m00i=m[1], m01r=m[2], m01i=m[3];
        const float m10r=m[4], m10i=m[5], m11r=m[6], m11i=m[7];
        #pragma unroll
        for (int k = 0; k < 16; ++k){
            if (k & (1 << lb)) continue;
            const int k1 = k | (1 << lb);
            const float2 a = s[k], bq = s[k1];
            s[k]  = make_float2(m00r*a.x - m00i*a.y + m01r*bq.x - m01i*bq.y,
                                m00r*a.y + m00i*a.x + m01r*bq.y + m01i*bq.x);
            s[k1] = make_float2(m10r*a.x - m10i*a.y + m11r*bq.x - m11i*bq.y,
                                m10r*a.y + m10i*a.x + m11r*bq.y + m11i*bq.x);
        }
    }
}

extern "C" __global__ void __launch_bounds__(256)
qlstm_kernel(const float* __restrict__ x,  const float* __restrict__ h0,
             const float* __restrict__ c0, const float* __restrict__ qw,
             const float* __restrict__ Wf, const float* __restrict__ bfp,
             const float* __restrict__ Wi, const float* __restrict__ bip,
             const float* __restrict__ Wc, const float* __restrict__ bcp,
             const float* __restrict__ Wo, const float* __restrict__ bop,
             float* __restrict__ out)
{
    __shared__ float2 S[NS];            // state, global-index order (swizzled)
    __shared__ float mats[2][NQ][8];    // Rot matrices per layer/wire
    __shared__ float hs[HH], cs[HH];
    __shared__ float red[16];

    const int b   = blockIdx.x;
    const int tid = threadIdx.x;

    // Rot matrices (PennyLane Rot = RZ(om) RY(th) RZ(phi))
    if (tid < 2*NQ){
        const int l = tid / NQ, w = tid % NQ;
        const float phi = qw[(l*NQ + w)*3 + 0];
        const float th  = qw[(l*NQ + w)*3 + 1];
        const float om  = qw[(l*NQ + w)*3 + 2];
        float cth, sth, cap, sap, cam, sam;
        sincosf(0.5f*th, &sth, &cth);
        sincosf(0.5f*(phi+om), &sap, &cap);
        sincosf(0.5f*(phi-om), &sam, &cam);
        float* m = mats[l][w];
        m[0] =  cap*cth;  m[1] = -sap*cth;   // m00 = e^{-i(phi+om)/2} c
        m[2] = -cam*sth;  m[3] = -sam*sth;   // m01 = -conj(em) s
        m[4] =  cam*sth;  m[5] = -sam*sth;   // m10 = em s
        m[6] =  cap*cth;  m[7] =  sap*cth;   // m11 = conj(ep) c
    }
    float wf=0,bfv=0,wi=0,biv=0,wc=0,bcv=0,wo=0,bov=0;
    if (tid < HH){
        hs[tid] = h0[b*HH + tid];  cs[tid] = c0[b*HH + tid];
        wf=Wf[tid]; bfv=bfp[tid]; wi=Wi[tid]; biv=bip[tid];
        wc=Wc[tid]; bcv=bcp[tid]; wo=Wo[tid]; bov=bop[tid];
    }
    __syncthreads();

    constexpr unsigned M0=maskM(0), M1=maskM(1), M2=maskM(2), M3=maskM(3);
    const float sg0 = (__builtin_parity(tid & (M0 & 0xFFu)) ? -1.f : 1.f);
    const float sg1 = (__builtin_parity(tid & (M1 & 0xFFu)) ? -1.f : 1.f);
    const float sg2 = (__builtin_parity(tid & (M2 & 0xFFu)) ? -1.f : 1.f);
    const float sg3 = (__builtin_parity(tid & (M3 & 0xFFu)) ? -1.f : 1.f);
    const int f0hi = (int)F0closed((unsigned)(tid << 4));   // F0 is XOR-linear
    const int tlo = tid & 0xF, thi = tid >> 4;

    float2 amp[16];

    #pragma unroll 1
    for (int t = 0; t < TT; ++t){
        // ---- product state = AngleEmbedding(RX) composed with layer-0 Rot ----
        float2 P = make_float2(1.f, 0.f);
        float2 v0s[4], v1s[4];
        #pragma unroll
        for (int w = 0; w < NQ; ++w){
            const float a = (w < 8) ? x[(b*TT + t)*8 + w] : hs[w - 8];
            float ca, sa;
            sincosf(0.5f*a, &sa, &ca);
            const float* m = mats[0][w];
            // v = M0_w @ (cos, -i sin)
            const float2 v0 = make_float2(m[0]*ca + m[3]*sa, m[1]*ca - m[2]*sa);
            const float2 v1 = make_float2(m[4]*ca + m[7]*sa, m[5]*ca - m[6]*sa);
            if (w < 8){
                const int sel = (tid >> (7 - w)) & 1;   // i bit (11-w) = tid bit (7-w)
                P = cmul(P, sel ? v1 : v0);
            } else {
                v0s[w-8] = v0; v1s[w-8] = v1;
            }
        }
        {   // amp[k] = P * v8[k>>3] * v9[(k>>2)&1] * v10[(k>>1)&1] * v11[k&1]
            const float2 a0 = cmul(P, v0s[0]), a1 = cmul(P, v1s[0]);
            float2 bbq[4], ccq[4];
            bbq[0]=cmul(a0,v0s[1]); bbq[1]=cmul(a0,v1s[1]);
            bbq[2]=cmul(a1,v0s[1]); bbq[3]=cmul(a1,v1s[1]);
            ccq[0]=cmul(v0s[2],v0s[3]); ccq[1]=cmul(v0s[2],v1s[3]);
            ccq[2]=cmul(v1s[2],v0s[3]); ccq[3]=cmul(v1s[2],v1s[3]);
            #pragma unroll
            for (int k = 0; k < 16; ++k) amp[k] = cmul(bbq[k>>2], ccq[k&3]);
        }

        // ---- CNOT layer 0 (gather) + 12 layer-1 Rot gates in 3 locality rounds ----
        #pragma unroll
        for (int k = 0; k < 16; ++k) S[swz((tid<<4)|k)] = amp[k];
        __syncthreads();
        #pragma unroll
        for (int k = 0; k < 16; ++k)
            amp[k] = S[swz(f0hi ^ (int)F0closed((unsigned)k))];  // s'[i]=s[F0(i)]
        rot4(amp, mats[1], 11);            // global bits 0..3 -> wires 11..8
        __syncthreads();
        #pragma unroll
        for (int k = 0; k < 16; ++k) S[swz((tid<<4)|k)] = amp[k];
        __syncthreads();
        #pragma unroll
        for (int k = 0; k < 16; ++k) amp[k] = S[swz((thi<<8)|(k<<4)|tlo)];
        rot4(amp, mats[1], 7);             // global bits 4..7 -> wires 7..4
        __syncthreads();
        #pragma unroll
        for (int k = 0; k < 16; ++k) S[swz((thi<<8)|(k<<4)|tlo)] = amp[k];
        __syncthreads();
        #pragma unroll
        for (int k = 0; k < 16; ++k) amp[k] = S[swz((k<<8)|tid)];
        rot4(amp, mats[1], 3);             // global bits 8..11 -> wires 3..0

        // ---- CNOT layer 1 folded into <Z_k> via parity masks; j = (k<<8)|tid ----
        float p0=0.f, p1=0.f, p2=0.f, p3=0.f;
        #pragma unroll
        for (int k = 0; k < 16; ++k){
            const float p = amp[k].x*amp[k].x + amp[k].y*amp[k].y;
            p0 += (__builtin_parity((unsigned)k & (M0>>8)) ? -p : p);
            p1 += (__builtin_parity((unsigned)k & (M1>>8)) ? -p : p);
            p2 += (__builtin_parity((unsigned)k & (M2>>8)) ? -p : p);
            p3 += (__builtin_parity((unsigned)k & (M3>>8)) ? -p : p);
        }
        p0 *= sg0; p1 *= sg1; p2 *= sg2; p3 *= sg3;
        #pragma unroll
        for (int mm = 1; mm < 64; mm <<= 1){
            p0 += __shfl_xor(p0, mm, 64);
            p1 += __shfl_xor(p1, mm, 64);
            p2 += __shfl_xor(p2, mm, 64);
            p3 += __shfl_xor(p3, mm, 64);
        }
        if ((tid & 63) == 0){
            const int wv = tid >> 6;
            red[wv*4+0]=p0; red[wv*4+1]=p1; red[wv*4+2]=p2; red[wv*4+3]=p3;
        }
        __syncthreads();

        // ---- LSTM gate update (full H=128) ----
        if (tid < HH){
            const float q0 = red[0]+red[4]+red[8]+red[12];
            const float q1 = red[1]+red[5]+red[9]+red[13];
            const float q2 = red[2]+red[6]+red[10]+red[14];
            const float q3 = red[3]+red[7]+red[11]+red[15];
            const float fg = 1.f/(1.f + expf(-(q0*wf + bfv)));
            const float ig = 1.f/(1.f + expf(-(q1*wi + biv)));
            const float cg = tanhf(q2*wc + bcv);
            const float og = 1.f/(1.f + expf(-(q3*wo + bov)));
            const float cn = fg*cs[tid] + ig*cg;
            cs[tid] = cn;
            hs[tid] = og * tanhf(cn);
        }
        __syncthreads();
    }

    if (tid < HH){
        out[b*HH + tid]         = hs[tid];
        out[BB*HH + b*HH + tid] = cs[tid];
    }
}

extern "C" void kernel_launch(void* const* d_in, const int* in_sizes, int n_in,
                              void* d_out, int out_size, void* d_ws, size_t ws_size,
                              hipStream_t stream)
{
    (void)in_sizes; (void)n_in; (void)d_ws; (void)ws_size; (void)out_size;
    const float* x  = (const float*)d_in[0];
    const float* h0 = (const float*)d_in[1];
    const float* c0 = (const float*)d_in[2];
    const float* qw = (const float*)d_in[3];
    const float* Wf = (const float*)d_in[4];
    const float* bf = (const float*)d_in[5];
    const float* Wi = (const float*)d_in[6];
    const float* bi = (const float*)d_in[7];
    const float* Wc = (const float*)d_in[8];
    const float* bc = (const float*)d_in[9];
    const float* Wo = (const float*)d_in[10];
    const float* bo = (const float*)d_in[11];
    qlstm_kernel<<<BB, 256, 0, stream>>>(x, h0, c0, qw, Wf, bf, Wi, bi,
                                         Wc, bc, Wo, bo, (float*)d_out);
}

// Round 3
// 175.319 us; speedup vs baseline: 1.3260x; 1.3260x over previous
//
#include <hip/hip_runtime.h>
#include <math.h>

#define NQ 12
#define NS 4096
#define TT 32
#define BB 256
#define HH 128
#define NT 512

// ---------- compile-time CNOT-layer permutations (exactly per reference _cnot) ----------
constexpr unsigned cnot_g(unsigned x, int w, int r){
    int pc = 11 - w;                    // control wire w -> bit 11-w
    int pt = 11 - ((w + r) % 12);       // target wire (w+r)%12
    return x ^ (((x >> pc) & 1u) << pt);
}
constexpr unsigned Fperm(unsigned i, int r){      // new[i] = old[Fperm(i,r)]
    unsigned x = i;
    for (int w = 11; w >= 0; --w) x = cnot_g(x, w, r);
    return x;
}
constexpr unsigned Finv(unsigned i, int r){
    unsigned x = i;
    for (int w = 0; w < 12; ++w) x = cnot_g(x, w, r);
    return x;
}
constexpr unsigned F0closed(unsigned i){          // Fperm(.,1) closed form
    return i ^ ((i >> 1) & 0x7FFu) ^ ((i & 1u) << 10) ^ ((i & 1u) << 11);
}
// All maps GF(2)-linear -> basis equality implies equality everywhere (step-limit safe).
constexpr bool check_all(){
    for (int b = 0; b < NQ; ++b){
        const unsigned e = 1u << b;
        if (F0closed(e) != Fperm(e,1)) return false;
        if (Fperm(Finv(e,1),1) != e) return false;
        if (Fperm(Finv(e,2),2) != e) return false;
    }
    if (F0closed(0u) != 0u || Fperm(0u,1) != 0u || Finv(0u,2) != 0u) return false;
    if (F0closed(0x5A3u) != Fperm(0x5A3u,1)) return false;
    if (Fperm(Finv(0xABCu,2),2) != 0xABCu) return false;
    return true;
}
static_assert(check_all(), "CNOT permutation closed forms wrong");
// parity masks: bit_{11-k}(Finv(j,2)) == parity(j & maskM(k))
constexpr unsigned maskM(int k){
    unsigned m = 0;
    for (int b = 0; b < NQ; ++b) m |= ((Finv(1u<<b, 2) >> (11 - k)) & 1u) << b;
    return m;
}

__device__ __forceinline__ float2 cmul(float2 a, float2 b){
    return make_float2(fmaf(a.x, b.x, -a.y * b.y), fmaf(a.x, b.y, a.y * b.x));
}
__device__ __forceinline__ int swz(int u){ return u ^ ((u >> 4) & 0xF); }

// 3 layer-1 Rot gates on the 3 thread-local bits; local bit lb <-> wire wtop-lb
__device__ __forceinline__ void rot3(float2* s, const float4 (*m1)[2], int wtop){
    #pragma unroll
    for (int lb = 0; lb < 3; ++lb){
        const float4 A  = m1[wtop - lb][0];   // m00r,m00i,m01r,m01i
        const float4 Bv = m1[wtop - lb][1];   // m10r,m10i,m11r,m11i
        #pragma unroll
        for (int k = 0; k < 8; ++k){
            if (k & (1 << lb)) continue;
            const int k1 = k | (1 << lb);
            const float2 a = s[k], bq = s[k1];
            s[k]  = make_float2(A.x*a.x - A.y*a.y + A.z*bq.x - A.w*bq.y,
                                A.x*a.y + A.y*a.x + A.z*bq.y + A.w*bq.x);
            s[k1] = make_float2(Bv.x*a.x - Bv.y*a.y + Bv.z*bq.x - Bv.w*bq.y,
                                Bv.x*a.y + Bv.y*a.x + Bv.z*bq.y + Bv.w*bq.x);
        }
    }
}

extern "C" __global__ void __launch_bounds__(NT)
qlstm_kernel(const float* __restrict__ x,  const float* __restrict__ h0,
             const float* __restrict__ c0, const float* __restrict__ qw,
             const float* __restrict__ Wf, const float* __restrict__ bfp,
             const float* __restrict__ Wi, const float* __restrict__ bip,
             const float* __restrict__ Wc, const float* __restrict__ bcp,
             const float* __restrict__ Wo, const float* __restrict__ bop,
             float* __restrict__ out)
{
    __shared__ float2 S0[NS], S1[NS];      // double-buffered state (swizzled)
    __shared__ float4 mats4[2][NQ][2];     // Rot matrices
    __shared__ float2 vv[NQ][2];           // per-wire product-state vectors (this step)
    __shared__ float  xs[TT*8];            // preloaded x for this batch element
    __shared__ float4 red4[8];             // per-wave partial expectations

    const int b   = blockIdx.x;
    const int tid = threadIdx.x;

    // ---- one-time init ----
    if (tid < 2*NQ){
        const int l = tid / NQ, w = tid % NQ;
        const float phi = qw[(l*NQ + w)*3 + 0];
        const float th  = qw[(l*NQ + w)*3 + 1];
        const float om  = qw[(l*NQ + w)*3 + 2];
        float cth, sth, cap, sap, cam, sam;
        sincosf(0.5f*th, &sth, &cth);
        sincosf(0.5f*(phi+om), &sap, &cap);
        sincosf(0.5f*(phi-om), &sam, &cam);
        mats4[l][w][0] = make_float4( cap*cth, -sap*cth, -cam*sth, -sam*sth);
        mats4[l][w][1] = make_float4( cam*sth, -sam*sth,  cap*cth,  sap*cth);
    }
    if (tid >= 256) xs[tid - 256] = x[b*(TT*8) + (tid - 256)];

    float wf=0,bfv=0,wi=0,biv=0,wc=0,bcv=0,wo=0,bov=0,c_reg=0,h_reg=0;
    if (tid < HH){
        c_reg = c0[b*HH + tid];  h_reg = h0[b*HH + tid];
        wf=Wf[tid]; bfv=bfp[tid]; wi=Wi[tid]; biv=bip[tid];
        wc=Wc[tid]; bcv=bcp[tid]; wo=Wo[tid]; bov=bop[tid];
    }
    __syncthreads();

    // vv for t=0: wires 0..7 from x (threads 128..135), wires 8..11 from h0 (threads 0..3)
    if (tid >= 128 && tid < 136){
        const int w = tid - 128;
        float sa, ca; sincosf(0.5f*xs[w], &sa, &ca);
        const float4 A = mats4[0][w][0], Bv = mats4[0][w][1];
        vv[w][0] = make_float2(A.x*ca + A.w*sa,  A.y*ca - A.z*sa);
        vv[w][1] = make_float2(Bv.x*ca + Bv.w*sa, Bv.y*ca - Bv.z*sa);
    }
    if (tid < 4){
        const int w = 8 + tid;
        float sa, ca; sincosf(0.5f*h0[b*HH + tid], &sa, &ca);
        const float4 A = mats4[0][w][0], Bv = mats4[0][w][1];
        vv[w][0] = make_float2(A.x*ca + A.w*sa,  A.y*ca - A.z*sa);
        vv[w][1] = make_float2(Bv.x*ca + Bv.w*sa, Bv.y*ca - Bv.z*sa);
    }
    __syncthreads();

    // ---- per-thread constants ----
    constexpr unsigned M0=maskM(0), M1=maskM(1), M2=maskM(2), M3=maskM(3);
    const float sg0 = (__builtin_parity(tid & (M0 & 0x1FFu)) ? -1.f : 1.f);
    const float sg1 = (__builtin_parity(tid & (M1 & 0x1FFu)) ? -1.f : 1.f);
    const float sg2 = (__builtin_parity(tid & (M2 & 0x1FFu)) ? -1.f : 1.f);
    const float sg3 = (__builtin_parity(tid & (M3 & 0x1FFu)) ? -1.f : 1.f);
    const int wA = swz(tid << 3);
    const int wB = swz(((tid >> 3) << 6) | (tid & 7));
    const int wC = swz(((tid >> 6) << 9) | (tid & 63));
    const int wD = swz(tid);
    // product-state selectors after F0: wire w in 2..8 -> tid bit (8-w) ^ (9-w)
    const int s2 = ((tid>>6) ^ (tid>>7)) & 1;
    const int s3 = ((tid>>5) ^ (tid>>6)) & 1;
    const int s4 = ((tid>>4) ^ (tid>>5)) & 1;
    const int s5 = ((tid>>3) ^ (tid>>4)) & 1;
    const int s6 = ((tid>>2) ^ (tid>>3)) & 1;
    const int s7 = ((tid>>1) ^ (tid>>2)) & 1;
    const int s8 = ( tid     ^ (tid>>1)) & 1;
    const int t8  = (tid >> 8) & 1;
    const int t78 = ((tid>>7) ^ (tid>>8)) & 1;
    const int t0  = tid & 1;
    const float2* vf = &vv[0][0];

    float2 amp[8];

    #pragma unroll 1
    for (int t = 0; t < TT; ++t){
        // ---- direct build of post-CNOT0 product state amps: amp[k] = prod[F0((tid<<3)|k)] ----
        const float2 e2 = vf[ 4+s2], e3 = vf[ 6+s3], e4 = vf[ 8+s4];
        const float2 e5 = vf[10+s5], e6 = vf[12+s6], e7 = vf[14+s7], e8 = vf[16+s8];
        const float2 Q  = cmul(cmul(cmul(e2,e3), cmul(e4,e5)), cmul(cmul(e6,e7), e8));
        const float2 v0a = vf[0], v0b = vf[1], v1a = vf[2], v1b = vf[3];
        const float2 ua0 = t8 ? v0b : v0a,  ua1 = t8 ? v0a : v0b;
        const float2 ub0 = t78 ? v1b : v1a, ub1 = t78 ? v1a : v1b;
        const float2 QU0 = cmul(Q, cmul(ua0, ub0));
        const float2 QU1 = cmul(Q, cmul(ua1, ub1));
        const float2 v9a = vf[18], v9b = vf[19];
        const float2 v9s0 = t0 ? v9b : v9a, v9s1 = t0 ? v9a : v9b;
        const float2 v10a = vf[20], v10b = vf[21], v11a = vf[22], v11b = vf[23];
        const float2 P2_0 = cmul(v10a, v11a), P2_1 = cmul(v10a, v11b);
        const float2 P2_2 = cmul(v10b, v11a), P2_3 = cmul(v10b, v11b);
        #pragma unroll
        for (int k = 0; k < 8; ++k){
            const int g = k ^ (k >> 1);
            const float2 base = (k & 1) ? QU1 : QU0;
            const float2 w9   = (g & 4) ? v9s1 : v9s0;
            const float2 p2   = (g&3)==0 ? P2_0 : (g&3)==1 ? P2_1 : (g&3)==2 ? P2_2 : P2_3;
            amp[k] = cmul(cmul(base, w9), p2);
        }

        // ---- 12 layer-1 Rot gates in 4 locality rounds ----
        rot3(amp, mats4[1], 11);                         // wires 11,10,9 (k bits 0..2)
        #pragma unroll
        for (int k = 0; k < 8; ++k) S0[wA ^ k] = amp[k];
        __syncthreads();
        #pragma unroll
        for (int k = 0; k < 8; ++k) amp[k] = S0[wB ^ ((k<<3) ^ (k>>1))];
        rot3(amp, mats4[1], 8);                          // wires 8,7,6
        #pragma unroll
        for (int k = 0; k < 8; ++k) S1[wB ^ ((k<<3) ^ (k>>1))] = amp[k];
        __syncthreads();
        #pragma unroll
        for (int k = 0; k < 8; ++k) amp[k] = S1[wC ^ ((k<<6) ^ ((k<<2)&0xF))];
        rot3(amp, mats4[1], 5);                          // wires 5,4,3
        #pragma unroll
        for (int k = 0; k < 8; ++k) S0[wC ^ ((k<<6) ^ ((k<<2)&0xF))] = amp[k];
        __syncthreads();
        #pragma unroll
        for (int k = 0; k < 8; ++k) amp[k] = S0[wD ^ (k<<9)];
        rot3(amp, mats4[1], 2);                          // wires 2,1,0

        // ---- CNOT layer 1 folded into <Z_g> via parity masks; j = (k<<9)|tid ----
        float p0=0.f, p1=0.f, p2s=0.f, p3=0.f;
        #pragma unroll
        for (int k = 0; k < 8; ++k){
            const float p = amp[k].x*amp[k].x + amp[k].y*amp[k].y;
            p0  += ((__builtin_popcount((unsigned)k & (M0>>9)) & 1) ? -p : p);
            p1  += ((__builtin_popcount((unsigned)k & (M1>>9)) & 1) ? -p : p);
            p2s += ((__builtin_popcount((unsigned)k & (M2>>9)) & 1) ? -p : p);
            p3  += ((__builtin_popcount((unsigned)k & (M3>>9)) & 1) ? -p : p);
        }
        p0 *= sg0; p1 *= sg1; p2s *= sg2; p3 *= sg3;
        #pragma unroll
        for (int mm = 1; mm < 64; mm <<= 1){
            p0  += __shfl_xor(p0,  mm, 64);
            p1  += __shfl_xor(p1,  mm, 64);
            p2s += __shfl_xor(p2s, mm, 64);
            p3  += __shfl_xor(p3,  mm, 64);
        }
        if ((tid & 63) == 0) red4[tid >> 6] = make_float4(p0, p1, p2s, p3);
        __syncthreads();

        // ---- LSTM update (regs) + next step's vv ----
        if (tid < HH){
            const float4 r0=red4[0], r1=red4[1], r2=red4[2], r3=red4[3];
            const float4 r4=red4[4], r5=red4[5], r6=red4[6], r7=red4[7];
            const float q0 = ((r0.x+r1.x)+(r2.x+r3.x)) + ((r4.x+r5.x)+(r6.x+r7.x));
            const float q1 = ((r0.y+r1.y)+(r2.y+r3.y)) + ((r4.y+r5.y)+(r6.y+r7.y));
            const float q2 = ((r0.z+r1.z)+(r2.z+r3.z)) + ((r4.z+r5.z)+(r6.z+r7.z));
            const float q3 = ((r0.w+r1.w)+(r2.w+r3.w)) + ((r4.w+r5.w)+(r6.w+r7.w));
            const float fg = 1.f/(1.f + expf(-(q0*wf + bfv)));
            const float ig = 1.f/(1.f + expf(-(q1*wi + biv)));
            const float cg = tanhf(q2*wc + bcv);
            const float og = 1.f/(1.f + expf(-(q3*wo + bov)));
            c_reg = fg*c_reg + ig*cg;
            h_reg = og * tanhf(c_reg);
            if (tid < 4){
                const int w = 8 + tid;
                float sa, ca; sincosf(0.5f*h_reg, &sa, &ca);
                const float4 A = mats4[0][w][0], Bv = mats4[0][w][1];
                vv[w][0] = make_float2(A.x*ca + A.w*sa,  A.y*ca - A.z*sa);
                vv[w][1] = make_float2(Bv.x*ca + Bv.w*sa, Bv.y*ca - Bv.z*sa);
            }
        }
        if (tid >= 128 && tid < 136){
            const int w  = tid - 128;
            const int tn = (t + 1 < TT) ? t + 1 : t;
            float sa, ca; sincosf(0.5f*xs[tn*8 + w], &sa, &ca);
            const float4 A = mats4[0][w][0], Bv = mats4[0][w][1];
            vv[w][0] = make_float2(A.x*ca + A.w*sa,  A.y*ca - A.z*sa);
            vv[w][1] = make_float2(Bv.x*ca + Bv.w*sa, Bv.y*ca - Bv.z*sa);
        }
        __syncthreads();
    }

    if (tid < HH){
        out[b*HH + tid]          = h_reg;
        out[BB*HH + b*HH + tid]  = c_reg;
    }
}

extern "C" void kernel_launch(void* const* d_in, const int* in_sizes, int n_in,
                              void* d_out, int out_size, void* d_ws, size_t ws_size,
                              hipStream_t stream)
{
    (void)in_sizes; (void)n_in; (void)d_ws; (void)ws_size; (void)out_size;
    const float* x  = (const float*)d_in[0];
    const float* h0 = (const float*)d_in[1];
    const float* c0 = (const float*)d_in[2];
    const float* qw = (const float*)d_in[3];
    const float* Wf = (const float*)d_in[4];
    const float* bf = (const float*)d_in[5];
    const float* Wi = (const float*)d_in[6];
    const float* bi = (const float*)d_in[7];
    const float* Wc = (const float*)d_in[8];
    const float* bc = (const float*)d_in[9];
    const float* Wo = (const float*)d_in[10];
    const float* bo = (const float*)d_in[11];
    qlstm_kernel<<<BB, NT, 0, stream>>>(x, h0, c0, qw, Wf, bf, Wi, bi,
                                        Wc, bc, Wo, bo, (float*)d_out);
}

// Round 4
// 141.189 us; speedup vs baseline: 1.6465x; 1.2417x over previous
//
#include <hip/hip_runtime.h>
#include <math.h>

#define NQ 12
#define NS 4096
#define TT 32
#define BB 256
#define HH 128
#define NT 512

typedef float v2f __attribute__((ext_vector_type(2)));

// ---------- compile-time CNOT-layer permutations (exactly per reference _cnot) ----------
constexpr unsigned cnot_g(unsigned x, int w, int r){
    int pc = 11 - w;                    // control wire w -> bit 11-w
    int pt = 11 - ((w + r) % 12);       // target wire (w+r)%12
    return x ^ (((x >> pc) & 1u) << pt);
}
constexpr unsigned Fperm(unsigned i, int r){      // new[i] = old[Fperm(i,r)]
    unsigned x = i;
    for (int w = 11; w >= 0; --w) x = cnot_g(x, w, r);
    return x;
}
constexpr unsigned Finv(unsigned i, int r){
    unsigned x = i;
    for (int w = 0; w < 12; ++w) x = cnot_g(x, w, r);
    return x;
}
constexpr unsigned F0closed(unsigned i){          // Fperm(.,1) closed form
    return i ^ ((i >> 1) & 0x7FFu) ^ ((i & 1u) << 10) ^ ((i & 1u) << 11);
}
// GF(2)-linear -> basis equality implies equality everywhere (constexpr step-limit safe).
constexpr bool check_all(){
    for (int b = 0; b < NQ; ++b){
        const unsigned e = 1u << b;
        if (F0closed(e) != Fperm(e,1)) return false;
        if (Fperm(Finv(e,1),1) != e) return false;
        if (Fperm(Finv(e,2),2) != e) return false;
    }
    if (F0closed(0u) != 0u || Fperm(0u,1) != 0u || Finv(0u,2) != 0u) return false;
    if (F0closed(0x5A3u) != Fperm(0x5A3u,1)) return false;
    if (Fperm(Finv(0xABCu,2),2) != 0xABCu) return false;
    return true;
}
static_assert(check_all(), "CNOT permutation closed forms wrong");
constexpr unsigned maskM(int k){
    unsigned m = 0;
    for (int b = 0; b < NQ; ++b) m |= ((Finv(1u<<b, 2) >> (11 - k)) & 1u) << b;
    return m;
}
constexpr unsigned gM0 = maskM(0), gM1 = maskM(1), gM2 = maskM(2), gM3 = maskM(3);
constexpr int sgn9(unsigned M, int K){ return __builtin_popcount((unsigned)K & (M >> 9)) & 1; }

// ---------- packed-fp32 complex helpers (VOP3P) ----------
// complex mul: lo = m.x*a.x - m.y*a.y ; hi = m.x*a.y + m.y*a.x   (symmetric in m,a)
__device__ __forceinline__ v2f pk_cmul(v2f m, v2f a){
    v2f t;
    asm("v_pk_mul_f32 %0, %1, %2 op_sel:[0,0] op_sel_hi:[0,1]"
        : "=v"(t) : "v"(m), "v"(a));
    asm("v_pk_fma_f32 %0, %1, %2, %0 op_sel:[1,1,0] op_sel_hi:[1,0,1] neg_lo:[1,0,0]"
        : "+v"(t) : "v"(m), "v"(a));
    return t;
}
// acc += m * a (complex)
__device__ __forceinline__ v2f pk_cfma(v2f m, v2f a, v2f acc){
    asm("v_pk_fma_f32 %0, %1, %2, %0 op_sel:[0,0,0] op_sel_hi:[0,1,1]"
        : "+v"(acc) : "v"(m), "v"(a));
    asm("v_pk_fma_f32 %0, %1, %2, %0 op_sel:[1,1,0] op_sel_hi:[1,0,1] neg_lo:[1,0,0]"
        : "+v"(acc) : "v"(m), "v"(a));
    return acc;
}
// acc += (NL? -pp : pp, NH? -pp : pp)
template<int NL, int NH>
__device__ __forceinline__ void pk_accsgn(v2f &acc, v2f ppb){
    if constexpr (NL==0 && NH==0)
        asm("v_pk_add_f32 %0, %1, %0" : "+v"(acc) : "v"(ppb));
    else if constexpr (NL==1 && NH==0)
        asm("v_pk_add_f32 %0, %1, %0 neg_lo:[1,0]" : "+v"(acc) : "v"(ppb));
    else if constexpr (NL==0 && NH==1)
        asm("v_pk_add_f32 %0, %1, %0 neg_hi:[1,0]" : "+v"(acc) : "v"(ppb));
    else
        asm("v_pk_add_f32 %0, %1, %0 neg_lo:[1,0] neg_hi:[1,0]" : "+v"(acc) : "v"(ppb));
}
template<int K>
__device__ __forceinline__ void expk(const v2f* amp, v2f &a01, v2f &a23){
    const float pp = fmaf(amp[K].x, amp[K].x, amp[K].y * amp[K].y);
    v2f ppb; ppb.x = pp; ppb.y = pp;
    pk_accsgn<sgn9(gM0,K), sgn9(gM1,K)>(a01, ppb);
    pk_accsgn<sgn9(gM2,K), sgn9(gM3,K)>(a23, ppb);
    if constexpr (K < 7) expk<K+1>(amp, a01, a23);
}

__device__ __forceinline__ int swz(int u){ return u ^ ((u >> 4) & 0xF); }

// 3 layer-1 Rot gates on the 3 thread-local bits; local bit lb <-> wire wtop-lb
// m1[w][0..3] = m00, m01, m10, m11 as (re, im)
__device__ __forceinline__ void rot3(v2f* s, const v2f (*m1)[4], int wtop){
    #pragma unroll
    for (int lb = 0; lb < 3; ++lb){
        const v2f M00 = m1[wtop-lb][0], M01 = m1[wtop-lb][1];
        const v2f M10 = m1[wtop-lb][2], M11 = m1[wtop-lb][3];
        #pragma unroll
        for (int k = 0; k < 8; ++k){
            if (k & (1 << lb)) continue;
            const int k1 = k | (1 << lb);
            const v2f a = s[k], b = s[k1];
            s[k]  = pk_cfma(M01, b, pk_cmul(M00, a));
            s[k1] = pk_cfma(M11, b, pk_cmul(M10, a));
        }
    }
}

extern "C" __global__ void __launch_bounds__(NT)
qlstm_kernel(const float* __restrict__ x,  const float* __restrict__ h0,
             const float* __restrict__ c0, const float* __restrict__ qw,
             const float* __restrict__ Wf, const float* __restrict__ bfp,
             const float* __restrict__ Wi, const float* __restrict__ bip,
             const float* __restrict__ Wc, const float* __restrict__ bcp,
             const float* __restrict__ Wo, const float* __restrict__ bop,
             float* __restrict__ out)
{
    __shared__ v2f S0[NS], S1[NS];         // double-buffered state (swizzled)
    __shared__ v2f matp[2][NQ][4];         // Rot matrices: m00,m01,m10,m11 (re,im)
    __shared__ v2f vv[NQ][2];              // per-wire product-state vectors (this step)
    __shared__ float xs[TT*8];             // preloaded x for this batch element
    __shared__ float4 red4[8];             // per-wave partial expectations

    const int b   = blockIdx.x;
    const int tid = threadIdx.x;

    // ---- one-time init ----
    if (tid < 2*NQ){
        const int l = tid / NQ, w = tid % NQ;
        const float phi = qw[(l*NQ + w)*3 + 0];
        const float th  = qw[(l*NQ + w)*3 + 1];
        const float om  = qw[(l*NQ + w)*3 + 2];
        float cth, sth, cap, sap, cam, sam;
        sincosf(0.5f*th, &sth, &cth);
        sincosf(0.5f*(phi+om), &sap, &cap);
        sincosf(0.5f*(phi-om), &sam, &cam);
        v2f m00; m00.x =  cap*cth; m00.y = -sap*cth;
        v2f m01; m01.x = -cam*sth; m01.y = -sam*sth;
        v2f m10; m10.x =  cam*sth; m10.y = -sam*sth;
        v2f m11; m11.x =  cap*cth; m11.y =  sap*cth;
        matp[l][w][0] = m00; matp[l][w][1] = m01;
        matp[l][w][2] = m10; matp[l][w][3] = m11;
    }
    if (tid >= 256) xs[tid - 256] = x[b*(TT*8) + (tid - 256)];

    float wf=0,bfv=0,wi=0,biv=0,wc=0,bcv=0,wo=0,bov=0,c_reg=0,h_reg=0;
    if (tid < HH){
        c_reg = c0[b*HH + tid];  h_reg = h0[b*HH + tid];
        wf=Wf[tid]; bfv=bfp[tid]; wi=Wi[tid]; biv=bip[tid];
        wc=Wc[tid]; bcv=bcp[tid]; wo=Wo[tid]; bov=bop[tid];
    }
    __syncthreads();

    // vv for t=0: wires 0..7 from x (threads 128..135), wires 8..11 from h0 (threads 0..3)
    if (tid >= 128 && tid < 136){
        const int w = tid - 128;
        float sa, ca; sincosf(0.5f*xs[w], &sa, &ca);
        const v2f M00=matp[0][w][0], M01=matp[0][w][1], M10=matp[0][w][2], M11=matp[0][w][3];
        v2f t0v; t0v.x = M00.x*ca + M01.y*sa; t0v.y = M00.y*ca - M01.x*sa;
        v2f t1v; t1v.x = M10.x*ca + M11.y*sa; t1v.y = M10.y*ca - M11.x*sa;
        vv[w][0] = t0v; vv[w][1] = t1v;
    }
    if (tid < 4){
        const int w = 8 + tid;
        float sa, ca; sincosf(0.5f*h0[b*HH + tid], &sa, &ca);
        const v2f M00=matp[0][w][0], M01=matp[0][w][1], M10=matp[0][w][2], M11=matp[0][w][3];
        v2f t0v; t0v.x = M00.x*ca + M01.y*sa; t0v.y = M00.y*ca - M01.x*sa;
        v2f t1v; t1v.x = M10.x*ca + M11.y*sa; t1v.y = M10.y*ca - M11.x*sa;
        vv[w][0] = t0v; vv[w][1] = t1v;
    }
    __syncthreads();

    // ---- per-thread constants ----
    const float sg0 = (__builtin_parity(tid & (gM0 & 0x1FFu)) ? -1.f : 1.f);
    const float sg1 = (__builtin_parity(tid & (gM1 & 0x1FFu)) ? -1.f : 1.f);
    const float sg2 = (__builtin_parity(tid & (gM2 & 0x1FFu)) ? -1.f : 1.f);
    const float sg3 = (__builtin_parity(tid & (gM3 & 0x1FFu)) ? -1.f : 1.f);
    const int wA = swz(tid << 3);
    const int wB = swz(((tid >> 3) << 6) | (tid & 7));
    const int wC = swz(((tid >> 6) << 9) | (tid & 63));
    const int wD = swz(tid);
    // product-state selectors after F0: wire w in 2..8 -> tid bit (8-w) ^ (9-w)
    const int s2 = ((tid>>6) ^ (tid>>7)) & 1;
    const int s3 = ((tid>>5) ^ (tid>>6)) & 1;
    const int s4 = ((tid>>4) ^ (tid>>5)) & 1;
    const int s5 = ((tid>>3) ^ (tid>>4)) & 1;
    const int s6 = ((tid>>2) ^ (tid>>3)) & 1;
    const int s7 = ((tid>>1) ^ (tid>>2)) & 1;
    const int s8 = ( tid     ^ (tid>>1)) & 1;
    const int t8  = (tid >> 8) & 1;
    const int t78 = ((tid>>7) ^ (tid>>8)) & 1;
    const int t0  = tid & 1;
    const v2f* vf = &vv[0][0];

    v2f amp[8];

    #pragma unroll 1
    for (int t = 0; t < TT; ++t){
        // ---- direct build of post-CNOT0 product state amps: amp[k] = prod[F0((tid<<3)|k)] ----
        const v2f e2 = vf[ 4+s2], e3 = vf[ 6+s3], e4 = vf[ 8+s4];
        const v2f e5 = vf[10+s5], e6 = vf[12+s6], e7 = vf[14+s7], e8 = vf[16+s8];
        const v2f Q  = pk_cmul(pk_cmul(pk_cmul(e2,e3), pk_cmul(e4,e5)),
                               pk_cmul(pk_cmul(e6,e7), e8));
        const v2f v0a = vf[0], v0b = vf[1], v1a = vf[2], v1b = vf[3];
        const v2f ua0 = t8 ? v0b : v0a,  ua1 = t8 ? v0a : v0b;
        const v2f ub0 = t78 ? v1b : v1a, ub1 = t78 ? v1a : v1b;
        const v2f QU0 = pk_cmul(Q, pk_cmul(ua0, ub0));
        const v2f QU1 = pk_cmul(Q, pk_cmul(ua1, ub1));
        const v2f v9a = vf[18], v9b = vf[19];
        const v2f v9s0 = t0 ? v9b : v9a, v9s1 = t0 ? v9a : v9b;
        const v2f v10a = vf[20], v10b = vf[21], v11a = vf[22], v11b = vf[23];
        const v2f P2_0 = pk_cmul(v10a, v11a), P2_1 = pk_cmul(v10a, v11b);
        const v2f P2_2 = pk_cmul(v10b, v11a), P2_3 = pk_cmul(v10b, v11b);
        #pragma unroll
        for (int k = 0; k < 8; ++k){
            const int g = k ^ (k >> 1);
            const v2f base = (k & 1) ? QU1 : QU0;
            const v2f w9   = (g & 4) ? v9s1 : v9s0;
            const v2f p2   = (g&3)==0 ? P2_0 : (g&3)==1 ? P2_1 : (g&3)==2 ? P2_2 : P2_3;
            amp[k] = pk_cmul(pk_cmul(base, w9), p2);
        }

        // ---- 12 layer-1 Rot gates in 4 locality rounds ----
        rot3(amp, matp[1], 11);                          // wires 11,10,9 (k bits 0..2)
        #pragma unroll
        for (int k = 0; k < 8; ++k) S0[wA ^ k] = amp[k];
        __syncthreads();
        #pragma unroll
        for (int k = 0; k < 8; ++k) amp[k] = S0[wB ^ ((k<<3) ^ (k>>1))];
        rot3(amp, matp[1], 8);                           // wires 8,7,6
        #pragma unroll
        for (int k = 0; k < 8; ++k) S1[wB ^ ((k<<3) ^ (k>>1))] = amp[k];
        __syncthreads();
        #pragma unroll
        for (int k = 0; k < 8; ++k) amp[k] = S1[wC ^ ((k<<6) ^ ((k<<2)&0xF))];
        rot3(amp, matp[1], 5);                           // wires 5,4,3
        #pragma unroll
        for (int k = 0; k < 8; ++k) S0[wC ^ ((k<<6) ^ ((k<<2)&0xF))] = amp[k];
        __syncthreads();
        #pragma unroll
        for (int k = 0; k < 8; ++k) amp[k] = S0[wD ^ (k<<9)];
        rot3(amp, matp[1], 2);                           // wires 2,1,0

        // ---- CNOT layer 1 folded into <Z_g> via packed sign accumulation ----
        v2f a01; a01.x = 0.f; a01.y = 0.f;
        v2f a23; a23.x = 0.f; a23.y = 0.f;
        expk<0>(amp, a01, a23);
        float p0 = a01.x * sg0, p1 = a01.y * sg1;
        float p2s = a23.x * sg2, p3 = a23.y * sg3;
        #pragma unroll
        for (int mm = 1; mm < 64; mm <<= 1){
            p0  += __shfl_xor(p0,  mm, 64);
            p1  += __shfl_xor(p1,  mm, 64);
            p2s += __shfl_xor(p2s, mm, 64);
            p3  += __shfl_xor(p3,  mm, 64);
        }
        if ((tid & 63) == 0) red4[tid >> 6] = make_float4(p0, p1, p2s, p3);
        __syncthreads();

        // ---- LSTM update (regs) + next step's vv ----
        if (tid < HH){
            const float4 r0=red4[0], r1=red4[1], r2=red4[2], r3=red4[3];
            const float4 r4=red4[4], r5=red4[5], r6=red4[6], r7=red4[7];
            const float q0 = ((r0.x+r1.x)+(r2.x+r3.x)) + ((r4.x+r5.x)+(r6.x+r7.x));
            const float q1 = ((r0.y+r1.y)+(r2.y+r3.y)) + ((r4.y+r5.y)+(r6.y+r7.y));
            const float q2 = ((r0.z+r1.z)+(r2.z+r3.z)) + ((r4.z+r5.z)+(r6.z+r7.z));
            const float q3 = ((r0.w+r1.w)+(r2.w+r3.w)) + ((r4.w+r5.w)+(r6.w+r7.w));
            const float fg = 1.f/(1.f + expf(-(q0*wf + bfv)));
            const float ig = 1.f/(1.f + expf(-(q1*wi + biv)));
            const float cg = tanhf(q2*wc + bcv);
            const float og = 1.f/(1.f + expf(-(q3*wo + bov)));
            c_reg = fg*c_reg + ig*cg;
            h_reg = og * tanhf(c_reg);
            if (tid < 4){
                const int w = 8 + tid;
                float sa, ca; sincosf(0.5f*h_reg, &sa, &ca);
                const v2f M00=matp[0][w][0], M01=matp[0][w][1], M10=matp[0][w][2], M11=matp[0][w][3];
                v2f t0v; t0v.x = M00.x*ca + M01.y*sa; t0v.y = M00.y*ca - M01.x*sa;
                v2f t1v; t1v.x = M10.x*ca + M11.y*sa; t1v.y = M10.y*ca - M11.x*sa;
                vv[w][0] = t0v; vv[w][1] = t1v;
            }
        }
        if (tid >= 128 && tid < 136){
            const int w  = tid - 128;
            const int tn = (t + 1 < TT) ? t + 1 : t;
            float sa, ca; sincosf(0.5f*xs[tn*8 + w], &sa, &ca);
            const v2f M00=matp[0][w][0], M01=matp[0][w][1], M10=matp[0][w][2], M11=matp[0][w][3];
            v2f t0v; t0v.x = M00.x*ca + M01.y*sa; t0v.y = M00.y*ca - M01.x*sa;
            v2f t1v; t1v.x = M10.x*ca + M11.y*sa; t1v.y = M10.y*ca - M11.x*sa;
            vv[w][0] = t0v; vv[w][1] = t1v;
        }
        __syncthreads();
    }

    if (tid < HH){
        out[b*HH + tid]          = h_reg;
        out[BB*HH + b*HH + tid]  = c_reg;
    }
}

extern "C" void kernel_launch(void* const* d_in, const int* in_sizes, int n_in,
                              void* d_out, int out_size, void* d_ws, size_t ws_size,
                              hipStream_t stream)
{
    (void)in_sizes; (void)n_in; (void)d_ws; (void)ws_size; (void)out_size;
    const float* x  = (const float*)d_in[0];
    const float* h0 = (const float*)d_in[1];
    const float* c0 = (const float*)d_in[2];
    const float* qw = (const float*)d_in[3];
    const float* Wf = (const float*)d_in[4];
    const float* bf = (const float*)d_in[5];
    const float* Wi = (const float*)d_in[6];
    const float* bi = (const float*)d_in[7];
    const float* Wc = (const float*)d_in[8];
    const float* bc = (const float*)d_in[9];
    const float* Wo = (const float*)d_in[10];
    const float* bo = (const float*)d_in[11];
    qlstm_kernel<<<BB, NT, 0, stream>>>(x, h0, c0, qw, Wf, bf, Wi, bi,
                                        Wc, bc, Wo, bo, (float*)d_out);
}